// Round 1
// baseline (1605.264 us; speedup 1.0000x reference)
//
#include <hip/hip_runtime.h>

#define N_NODES 100000
#define N_EDGES 1600000
#define IN_DIM 128
#define OUT_DIM 64

// ---------------- Projection: h = h_init @ W1.T ----------------
// One thread per output row. W1 (64x128 fp32 = 32 KB) staged in LDS;
// all lanes read the same W element per step -> LDS broadcast, no conflicts.
__global__ __launch_bounds__(256) void proj_kernel(
    const float* __restrict__ h_init, const float* __restrict__ W1,
    float* __restrict__ h) {
  __shared__ float4 Ws4[OUT_DIM * IN_DIM / 4];  // 2048 float4 = 32 KB
  const float4* W14 = (const float4*)W1;
  for (int i = threadIdx.x; i < OUT_DIM * IN_DIM / 4; i += 256) Ws4[i] = W14[i];
  __syncthreads();

  int row = blockIdx.x * 256 + threadIdx.x;
  if (row >= N_NODES) return;

  const float4* xr = (const float4*)(h_init + (size_t)row * IN_DIM);
  float acc[OUT_DIM];
#pragma unroll
  for (int o = 0; o < OUT_DIM; o++) acc[o] = 0.f;

#pragma unroll 4
  for (int k4 = 0; k4 < IN_DIM / 4; k4++) {
    float4 x = xr[k4];
#pragma unroll
    for (int o = 0; o < OUT_DIM; o++) {
      float4 w = Ws4[o * (IN_DIM / 4) + k4];
      acc[o] += x.x * w.x + x.y * w.y + x.z * w.z + x.w * w.w;
    }
  }

  float4* outr = (float4*)(h + (size_t)row * OUT_DIM);
#pragma unroll
  for (int o4 = 0; o4 < OUT_DIM / 4; o4++)
    outr[o4] = make_float4(acc[4 * o4], acc[4 * o4 + 1], acc[4 * o4 + 2],
                           acc[4 * o4 + 3]);
}

// ---------------- Edge pass (single pass) ----------------
// 16 lanes per edge, float4 per lane (64 floats = OUT_DIM).
// h_diff[d] += ex * diff ; denom[d] += ex  (normalize in epilogue).
__global__ __launch_bounds__(256) void edge_kernel(
    const float* __restrict__ h, const float* __restrict__ a,
    const int* __restrict__ src, const int* __restrict__ dst,
    float* __restrict__ h_diff, float* __restrict__ denom) {
  int t = blockIdx.x * 256 + threadIdx.x;
  int e = t >> 4;
  int lane = threadIdx.x & 15;
  if (e >= N_EDGES) return;

  int s = src[e];
  int d = dst[e];
  const float4* h4 = (const float4*)h;
  float4 hs = h4[(size_t)s * (OUT_DIM / 4) + lane];
  float4 hd = h4[(size_t)d * (OUT_DIM / 4) + lane];
  float4 df;
  df.x = hd.x - hs.x;
  df.y = hd.y - hs.y;
  df.z = hd.z - hs.z;
  df.w = hd.w - hs.w;

  float4 av = ((const float4*)a)[lane];
  float p = df.x * av.x + df.y * av.y + df.z * av.z + df.w * av.w;
  // reduce across the 16-lane group (xor masks <16 stay inside the group)
  p += __shfl_xor(p, 1);
  p += __shfl_xor(p, 2);
  p += __shfl_xor(p, 4);
  p += __shfl_xor(p, 8);

  float ex = expf(tanhf(p));

  if (lane == 0) unsafeAtomicAdd(&denom[d], ex);
  float* hp = h_diff + (size_t)d * OUT_DIM + lane * 4;
  unsafeAtomicAdd(hp + 0, ex * df.x);
  unsafeAtomicAdd(hp + 1, ex * df.y);
  unsafeAtomicAdd(hp + 2, ex * df.z);
  unsafeAtomicAdd(hp + 3, ex * df.w);
}

// ---------------- Epilogue: out = relu(h + h_diff / denom) ----------------
__global__ __launch_bounds__(256) void final_kernel(
    const float* __restrict__ h, const float* __restrict__ h_diff,
    const float* __restrict__ denom, float* __restrict__ out) {
  int i = blockIdx.x * 256 + threadIdx.x;  // float4 index
  if (i >= N_NODES * OUT_DIM / 4) return;
  int node = i >> 4;
  float den = denom[node];
  float inv = den > 0.f ? 1.f / den : 0.f;
  float4 hv = ((const float4*)h)[i];
  float4 dv = ((const float4*)h_diff)[i];
  float4 r;
  r.x = fmaxf(hv.x + dv.x * inv, 0.f);
  r.y = fmaxf(hv.y + dv.y * inv, 0.f);
  r.z = fmaxf(hv.z + dv.z * inv, 0.f);
  r.w = fmaxf(hv.w + dv.w * inv, 0.f);
  ((float4*)out)[i] = r;
}

extern "C" void kernel_launch(void* const* d_in, const int* in_sizes, int n_in,
                              void* d_out, int out_size, void* d_ws,
                              size_t ws_size, hipStream_t stream) {
  const float* h_init = (const float*)d_in[0];
  const float* W1 = (const float*)d_in[1];
  const float* a = (const float*)d_in[2];
  const int* src = (const int*)d_in[3];
  const int* dst = (const int*)d_in[4];
  float* out = (float*)d_out;

  float* ws = (float*)d_ws;
  float* h_diff = ws;                                   // 6.4M floats
  float* denom = ws + (size_t)N_NODES * OUT_DIM;        // 100K floats
  float* h = denom + N_NODES;                           // 6.4M floats
  // total ws use: 12.9M floats = 51.6 MB

  // zero the accumulators (h_diff + denom are contiguous)
  hipMemsetAsync(h_diff, 0,
                 ((size_t)N_NODES * OUT_DIM + N_NODES) * sizeof(float),
                 stream);

  proj_kernel<<<(N_NODES + 255) / 256, 256, 0, stream>>>(h_init, W1, h);
  edge_kernel<<<N_EDGES / 16, 256, 0, stream>>>(h, a, src, dst, h_diff, denom);
  final_kernel<<<(N_NODES * OUT_DIM / 4 + 255) / 256, 256, 0, stream>>>(
      h, h_diff, denom, out);
}

// Round 2
// 633.828 us; speedup vs baseline: 2.5326x; 2.5326x over previous
//
#include <hip/hip_runtime.h>

#define N_NODES 100000
#define N_EDGES 1600000
#define IN_DIM 128
#define OUT_DIM 64
#define SCAN_THREADS 1024

// ---------------- Projection: h = h_init @ W1.T ----------------
__global__ __launch_bounds__(256) void proj_kernel(
    const float* __restrict__ h_init, const float* __restrict__ W1,
    float* __restrict__ h) {
  __shared__ float4 Ws4[OUT_DIM * IN_DIM / 4];  // 32 KB
  const float4* W14 = (const float4*)W1;
  for (int i = threadIdx.x; i < OUT_DIM * IN_DIM / 4; i += 256) Ws4[i] = W14[i];
  __syncthreads();

  int row = blockIdx.x * 256 + threadIdx.x;
  if (row >= N_NODES) return;

  const float4* xr = (const float4*)(h_init + (size_t)row * IN_DIM);
  float acc[OUT_DIM];
#pragma unroll
  for (int o = 0; o < OUT_DIM; o++) acc[o] = 0.f;

#pragma unroll 4
  for (int k4 = 0; k4 < IN_DIM / 4; k4++) {
    float4 x = xr[k4];
#pragma unroll
    for (int o = 0; o < OUT_DIM; o++) {
      float4 w = Ws4[o * (IN_DIM / 4) + k4];
      acc[o] += x.x * w.x + x.y * w.y + x.z * w.z + x.w * w.w;
    }
  }

  float4* outr = (float4*)(h + (size_t)row * OUT_DIM);
#pragma unroll
  for (int o4 = 0; o4 < OUT_DIM / 4; o4++)
    outr[o4] = make_float4(acc[4 * o4], acc[4 * o4 + 1], acc[4 * o4 + 2],
                           acc[4 * o4 + 3]);
}

// ---------------- Counting sort of edges by dst ----------------
__global__ __launch_bounds__(256) void hist_kernel(const int* __restrict__ dst,
                                                   int* __restrict__ deg) {
  int e = blockIdx.x * 256 + threadIdx.x;
  if (e < N_EDGES) atomicAdd(&deg[dst[e]], 1);
}

// Single-workgroup exclusive scan: deg[N] -> offsets[N+1], cursor[N] (copy).
__global__ __launch_bounds__(SCAN_THREADS) void scan_kernel(
    const int* __restrict__ deg, int* __restrict__ offsets,
    int* __restrict__ cursor) {
  __shared__ int sums[SCAN_THREADS];
  int t = threadIdx.x;
  const int chunk = (N_NODES + SCAN_THREADS - 1) / SCAN_THREADS;
  int begin = t * chunk;
  int end = begin + chunk;
  if (end > N_NODES) end = N_NODES;
  int s = 0;
  for (int i = begin; i < end; i++) s += deg[i];
  sums[t] = s;
  __syncthreads();
  // Hillis-Steele inclusive scan over per-thread sums
  for (int off = 1; off < SCAN_THREADS; off <<= 1) {
    int v = (t >= off) ? sums[t - off] : 0;
    __syncthreads();
    sums[t] += v;
    __syncthreads();
  }
  int run = (t == 0) ? 0 : sums[t - 1];
  for (int i = begin; i < end; i++) {
    offsets[i] = run;
    cursor[i] = run;
    run += deg[i];
  }
  if (t == SCAN_THREADS - 1) offsets[N_NODES] = run;  // == N_EDGES
}

__global__ __launch_bounds__(256) void scatter_kernel(
    const int* __restrict__ src, const int* __restrict__ dst,
    int* __restrict__ cursor, int* __restrict__ sorted_src) {
  int e = blockIdx.x * 256 + threadIdx.x;
  if (e < N_EDGES) {
    int pos = atomicAdd(&cursor[dst[e]], 1);
    sorted_src[pos] = src[e];
  }
}

// ---------------- Gather + softmax + epilogue (one wave per node) ----------
// 4 subgroups of 16 lanes; each subgroup handles one edge per iteration,
// float4 per lane covers the 64-dim feature. No fp32 atomics anywhere.
__global__ __launch_bounds__(256) void gather_kernel(
    const float* __restrict__ h, const float* __restrict__ a,
    const int* __restrict__ offsets, const int* __restrict__ sorted_src,
    float* __restrict__ out) {
  int wave = (blockIdx.x * 256 + threadIdx.x) >> 6;
  int lane = threadIdx.x & 63;
  if (wave >= N_NODES) return;
  int n = wave;
  int beg = offsets[n];
  int end = offsets[n + 1];
  int g = lane >> 4;    // subgroup id 0..3
  int l16 = lane & 15;  // lane within subgroup

  const float4* h4 = (const float4*)h;
  float4 hd = h4[(size_t)n * (OUT_DIM / 4) + l16];
  float4 av = ((const float4*)a)[l16];

  float4 acc = make_float4(0.f, 0.f, 0.f, 0.f);
  float den = 0.f;

  for (int i = beg + g; i < end; i += 4) {
    int s = sorted_src[i];
    float4 hs = h4[(size_t)s * (OUT_DIM / 4) + l16];
    float4 df;
    df.x = hd.x - hs.x;
    df.y = hd.y - hs.y;
    df.z = hd.z - hs.z;
    df.w = hd.w - hs.w;
    float p = df.x * av.x + df.y * av.y + df.z * av.z + df.w * av.w;
    // reduce within the 16-lane subgroup (xor masks < 16 stay inside)
    p += __shfl_xor(p, 1);
    p += __shfl_xor(p, 2);
    p += __shfl_xor(p, 4);
    p += __shfl_xor(p, 8);
    float ex = expf(tanhf(p));
    den += ex;
    acc.x += ex * df.x;
    acc.y += ex * df.y;
    acc.z += ex * df.z;
    acc.w += ex * df.w;
  }

  // combine the 4 subgroups (same l16, different g)
  acc.x += __shfl_xor(acc.x, 16);
  acc.x += __shfl_xor(acc.x, 32);
  acc.y += __shfl_xor(acc.y, 16);
  acc.y += __shfl_xor(acc.y, 32);
  acc.z += __shfl_xor(acc.z, 16);
  acc.z += __shfl_xor(acc.z, 32);
  acc.w += __shfl_xor(acc.w, 16);
  acc.w += __shfl_xor(acc.w, 32);
  den += __shfl_xor(den, 16);
  den += __shfl_xor(den, 32);

  if (g == 0) {
    float inv = den > 0.f ? 1.f / den : 0.f;
    float4 r;
    r.x = fmaxf(hd.x + acc.x * inv, 0.f);
    r.y = fmaxf(hd.y + acc.y * inv, 0.f);
    r.z = fmaxf(hd.z + acc.z * inv, 0.f);
    r.w = fmaxf(hd.w + acc.w * inv, 0.f);
    ((float4*)out)[(size_t)n * (OUT_DIM / 4) + l16] = r;
  }
}

extern "C" void kernel_launch(void* const* d_in, const int* in_sizes, int n_in,
                              void* d_out, int out_size, void* d_ws,
                              size_t ws_size, hipStream_t stream) {
  const float* h_init = (const float*)d_in[0];
  const float* W1 = (const float*)d_in[1];
  const float* a = (const float*)d_in[2];
  const int* src = (const int*)d_in[3];
  const int* dst = (const int*)d_in[4];
  float* out = (float*)d_out;

  // workspace layout
  float* h = (float*)d_ws;                              // 6.4M floats, 25.6 MB
  int* deg = (int*)(h + (size_t)N_NODES * OUT_DIM);     // 100K
  int* cursor = deg + N_NODES;                          // 100K
  int* offsets = cursor + N_NODES;                      // 100K+1
  int* sorted_src = offsets + (N_NODES + 1);            // 1.6M
  // total ~33 MB

  // zero the histogram (deg); cursor is filled by scan_kernel
  hipMemsetAsync(deg, 0, (size_t)N_NODES * sizeof(int), stream);

  proj_kernel<<<(N_NODES + 255) / 256, 256, 0, stream>>>(h_init, W1, h);
  hist_kernel<<<(N_EDGES + 255) / 256, 256, 0, stream>>>(dst, deg);
  scan_kernel<<<1, SCAN_THREADS, 0, stream>>>(deg, offsets, cursor);
  scatter_kernel<<<(N_EDGES + 255) / 256, 256, 0, stream>>>(src, dst, cursor,
                                                            sorted_src);
  gather_kernel<<<(N_NODES * 64 + 255) / 256, 256, 0, stream>>>(
      h, a, offsets, sorted_src, out);
}

// Round 3
// 429.831 us; speedup vs baseline: 3.7346x; 1.4746x over previous
//
#include <hip/hip_runtime.h>

#define N_NODES 100000
#define N_EDGES 1600000
#define IN_DIM 128
#define OUT_DIM 64
#define SCAN_BS 1024
#define SCAN_NBLK ((N_NODES + SCAN_BS - 1) / SCAN_BS)  // 98

// ---------------- Projection: h = h_init @ W1.T ----------------
__global__ __launch_bounds__(256) void proj_kernel(
    const float* __restrict__ h_init, const float* __restrict__ W1,
    float* __restrict__ h) {
  __shared__ float4 Ws4[OUT_DIM * IN_DIM / 4];  // 32 KB
  const float4* W14 = (const float4*)W1;
  for (int i = threadIdx.x; i < OUT_DIM * IN_DIM / 4; i += 256) Ws4[i] = W14[i];
  __syncthreads();

  int row = blockIdx.x * 256 + threadIdx.x;
  if (row >= N_NODES) return;

  const float4* xr = (const float4*)(h_init + (size_t)row * IN_DIM);
  float acc[OUT_DIM];
#pragma unroll
  for (int o = 0; o < OUT_DIM; o++) acc[o] = 0.f;

#pragma unroll 4
  for (int k4 = 0; k4 < IN_DIM / 4; k4++) {
    float4 x = xr[k4];
#pragma unroll
    for (int o = 0; o < OUT_DIM; o++) {
      float4 w = Ws4[o * (IN_DIM / 4) + k4];
      acc[o] += x.x * w.x + x.y * w.y + x.z * w.z + x.w * w.w;
    }
  }

  float4* outr = (float4*)(h + (size_t)row * OUT_DIM);
#pragma unroll
  for (int o4 = 0; o4 < OUT_DIM / 4; o4++)
    outr[o4] = make_float4(acc[4 * o4], acc[4 * o4 + 1], acc[4 * o4 + 2],
                           acc[4 * o4 + 3]);
}

// ---------------- Counting sort of edges by dst ----------------
__global__ __launch_bounds__(256) void hist_kernel(const int* __restrict__ dst,
                                                   int* __restrict__ deg) {
  int e = blockIdx.x * 256 + threadIdx.x;
  if (e < N_EDGES) atomicAdd(&deg[dst[e]], 1);
}

// Device-wide exclusive scan in 3 phases (full-GPU, each ~µs scale).
__global__ __launch_bounds__(SCAN_BS) void scan_reduce_kernel(
    const int* __restrict__ deg, int* __restrict__ bsum) {
  __shared__ int s[SCAN_BS];
  int i = blockIdx.x * SCAN_BS + threadIdx.x;
  s[threadIdx.x] = (i < N_NODES) ? deg[i] : 0;
  __syncthreads();
  for (int off = SCAN_BS / 2; off > 0; off >>= 1) {
    if (threadIdx.x < off) s[threadIdx.x] += s[threadIdx.x + off];
    __syncthreads();
  }
  if (threadIdx.x == 0) bsum[blockIdx.x] = s[0];
}

__global__ __launch_bounds__(128) void scan_base_kernel(
    const int* __restrict__ bsum, int* __restrict__ bbase) {
  __shared__ int s[128];
  int t = threadIdx.x;
  int v = (t < SCAN_NBLK) ? bsum[t] : 0;
  s[t] = v;
  __syncthreads();
  for (int off = 1; off < 128; off <<= 1) {
    int u = (t >= off) ? s[t - off] : 0;
    __syncthreads();
    s[t] += u;
    __syncthreads();
  }
  if (t < SCAN_NBLK) bbase[t] = s[t] - v;  // exclusive base per block
}

__global__ __launch_bounds__(SCAN_BS) void scan_final_kernel(
    const int* __restrict__ deg, const int* __restrict__ bbase,
    int* __restrict__ offsets, int* __restrict__ cursor) {
  __shared__ int s[SCAN_BS];
  int t = threadIdx.x;
  int i = blockIdx.x * SCAN_BS + t;
  int v = (i < N_NODES) ? deg[i] : 0;
  s[t] = v;
  __syncthreads();
  for (int off = 1; off < SCAN_BS; off <<= 1) {
    int u = (t >= off) ? s[t - off] : 0;
    __syncthreads();
    s[t] += u;
    __syncthreads();
  }
  if (i < N_NODES) {
    int excl = s[t] - v + bbase[blockIdx.x];
    offsets[i] = excl;
    cursor[i] = excl;
  }
  if (i == 0) offsets[N_NODES] = N_EDGES;
}

__global__ __launch_bounds__(256) void scatter_kernel(
    const int* __restrict__ src, const int* __restrict__ dst,
    int* __restrict__ cursor, int* __restrict__ sorted_src) {
  int e = blockIdx.x * 256 + threadIdx.x;
  if (e < N_EDGES) {
    int pos = atomicAdd(&cursor[dst[e]], 1);
    sorted_src[pos] = src[e];
  }
}

// ---------------- Gather + softmax + epilogue (one wave per node) ----------
__global__ __launch_bounds__(256) void gather_kernel(
    const float* __restrict__ h, const float* __restrict__ a,
    const int* __restrict__ offsets, const int* __restrict__ sorted_src,
    float* __restrict__ out) {
  int wave = (blockIdx.x * 256 + threadIdx.x) >> 6;
  int lane = threadIdx.x & 63;
  if (wave >= N_NODES) return;
  int n = wave;
  int beg = offsets[n];
  int end = offsets[n + 1];
  int g = lane >> 4;    // subgroup id 0..3
  int l16 = lane & 15;  // lane within subgroup

  const float4* h4 = (const float4*)h;
  float4 hd = h4[(size_t)n * (OUT_DIM / 4) + l16];
  float4 av = ((const float4*)a)[l16];

  float4 acc = make_float4(0.f, 0.f, 0.f, 0.f);
  float den = 0.f;

  for (int i = beg + g; i < end; i += 4) {
    int s = sorted_src[i];
    float4 hs = h4[(size_t)s * (OUT_DIM / 4) + l16];
    float4 df;
    df.x = hd.x - hs.x;
    df.y = hd.y - hs.y;
    df.z = hd.z - hs.z;
    df.w = hd.w - hs.w;
    float p = df.x * av.x + df.y * av.y + df.z * av.z + df.w * av.w;
    p += __shfl_xor(p, 1);
    p += __shfl_xor(p, 2);
    p += __shfl_xor(p, 4);
    p += __shfl_xor(p, 8);
    float ex = expf(tanhf(p));
    den += ex;
    acc.x += ex * df.x;
    acc.y += ex * df.y;
    acc.z += ex * df.z;
    acc.w += ex * df.w;
  }

  acc.x += __shfl_xor(acc.x, 16);
  acc.x += __shfl_xor(acc.x, 32);
  acc.y += __shfl_xor(acc.y, 16);
  acc.y += __shfl_xor(acc.y, 32);
  acc.z += __shfl_xor(acc.z, 16);
  acc.z += __shfl_xor(acc.z, 32);
  acc.w += __shfl_xor(acc.w, 16);
  acc.w += __shfl_xor(acc.w, 32);
  den += __shfl_xor(den, 16);
  den += __shfl_xor(den, 32);

  if (g == 0) {
    float inv = den > 0.f ? 1.f / den : 0.f;
    float4 r;
    r.x = fmaxf(hd.x + acc.x * inv, 0.f);
    r.y = fmaxf(hd.y + acc.y * inv, 0.f);
    r.z = fmaxf(hd.z + acc.z * inv, 0.f);
    r.w = fmaxf(hd.w + acc.w * inv, 0.f);
    ((float4*)out)[(size_t)n * (OUT_DIM / 4) + l16] = r;
  }
}

extern "C" void kernel_launch(void* const* d_in, const int* in_sizes, int n_in,
                              void* d_out, int out_size, void* d_ws,
                              size_t ws_size, hipStream_t stream) {
  const float* h_init = (const float*)d_in[0];
  const float* W1 = (const float*)d_in[1];
  const float* a = (const float*)d_in[2];
  const int* src = (const int*)d_in[3];
  const int* dst = (const int*)d_in[4];
  float* out = (float*)d_out;

  // workspace layout
  float* h = (float*)d_ws;                              // 6.4M floats, 25.6 MB
  int* deg = (int*)(h + (size_t)N_NODES * OUT_DIM);     // 100K
  int* cursor = deg + N_NODES;                          // 100K
  int* offsets = cursor + N_NODES;                      // 100K+1
  int* sorted_src = offsets + (N_NODES + 1);            // 1.6M
  int* bsum = sorted_src + N_EDGES;                     // 98
  int* bbase = bsum + SCAN_NBLK;                        // 98

  hipMemsetAsync(deg, 0, (size_t)N_NODES * sizeof(int), stream);

  proj_kernel<<<(N_NODES + 255) / 256, 256, 0, stream>>>(h_init, W1, h);
  hist_kernel<<<(N_EDGES + 255) / 256, 256, 0, stream>>>(dst, deg);
  scan_reduce_kernel<<<SCAN_NBLK, SCAN_BS, 0, stream>>>(deg, bsum);
  scan_base_kernel<<<1, 128, 0, stream>>>(bsum, bbase);
  scan_final_kernel<<<SCAN_NBLK, SCAN_BS, 0, stream>>>(deg, bbase, offsets,
                                                       cursor);
  scatter_kernel<<<(N_EDGES + 255) / 256, 256, 0, stream>>>(src, dst, cursor,
                                                            sorted_src);
  gather_kernel<<<(N_NODES * 64 + 255) / 256, 256, 0, stream>>>(
      h, a, offsets, sorted_src, out);
}

// Round 4
// 381.614 us; speedup vs baseline: 4.2065x; 1.1264x over previous
//
#include <hip/hip_runtime.h>

#define N_NODES 100000
#define N_EDGES 1600000
#define IN_DIM 128
#define OUT_DIM 64

#define NBUCK 391       // ceil(N_NODES/256); bucket = dst >> 8 (256 nodes each)
#define BIN_NBLK 100
#define BIN_CHUNK 16000  // BIN_NBLK * BIN_CHUNK == N_EDGES
#define CNT_TOTAL (NBUCK * BIN_NBLK)  // 39100

// ---------------- Projection: h = h_init @ W1.T ----------------
__global__ __launch_bounds__(256) void proj_kernel(
    const float* __restrict__ h_init, const float* __restrict__ W1,
    float* __restrict__ h) {
  __shared__ float4 Ws4[OUT_DIM * IN_DIM / 4];  // 32 KB
  const float4* W14 = (const float4*)W1;
  for (int i = threadIdx.x; i < OUT_DIM * IN_DIM / 4; i += 256) Ws4[i] = W14[i];
  __syncthreads();

  int row = blockIdx.x * 256 + threadIdx.x;
  if (row >= N_NODES) return;

  const float4* xr = (const float4*)(h_init + (size_t)row * IN_DIM);
  float acc[OUT_DIM];
#pragma unroll
  for (int o = 0; o < OUT_DIM; o++) acc[o] = 0.f;

#pragma unroll 4
  for (int k4 = 0; k4 < IN_DIM / 4; k4++) {
    float4 x = xr[k4];
#pragma unroll
    for (int o = 0; o < OUT_DIM; o++) {
      float4 w = Ws4[o * (IN_DIM / 4) + k4];
      acc[o] += x.x * w.x + x.y * w.y + x.z * w.z + x.w * w.w;
    }
  }

  float4* outr = (float4*)(h + (size_t)row * OUT_DIM);
#pragma unroll
  for (int o4 = 0; o4 < OUT_DIM / 4; o4++)
    outr[o4] = make_float4(acc[4 * o4], acc[4 * o4 + 1], acc[4 * o4 + 2],
                           acc[4 * o4 + 3]);
}

// ---------------- Phase 1a: per-(block,bucket) histogram ----------------
__global__ __launch_bounds__(256) void bin_count_kernel(
    const int* __restrict__ dst, int* __restrict__ blk_cnt) {
  __shared__ int hst[NBUCK];
  for (int i = threadIdx.x; i < NBUCK; i += 256) hst[i] = 0;
  __syncthreads();
  int beg = blockIdx.x * BIN_CHUNK;
  int end = min(beg + BIN_CHUNK, N_EDGES);
  for (int e = beg + threadIdx.x; e < end; e += 256)
    atomicAdd(&hst[dst[e] >> 8], 1);
  __syncthreads();
  for (int i = threadIdx.x; i < NBUCK; i += 256)
    blk_cnt[i * BIN_NBLK + blockIdx.x] = hst[i];  // bucket-major
}

// ---------------- Phase 1b: exclusive scan of blk_cnt (39,100 ints) -------
__global__ __launch_bounds__(1024) void scan_cnt_kernel(
    const int* __restrict__ blk_cnt, int* __restrict__ wbase) {
  __shared__ int sums[1024];
  int t = threadIdx.x;
  const int chunk = (CNT_TOTAL + 1023) / 1024;
  int beg = t * chunk;
  int end = min(beg + chunk, CNT_TOTAL);
  int s = 0;
  for (int i = beg; i < end; i++) s += blk_cnt[i];
  sums[t] = s;
  __syncthreads();
  for (int off = 1; off < 1024; off <<= 1) {
    int v = (t >= off) ? sums[t - off] : 0;
    __syncthreads();
    sums[t] += v;
    __syncthreads();
  }
  int run = (t == 0) ? 0 : sums[t - 1];
  for (int i = beg; i < end; i++) {
    int c = blk_cnt[i];
    wbase[i] = run;
    run += c;
  }
  if (t == 1023) wbase[CNT_TOTAL] = N_EDGES;  // sentinel
}

// ---------------- Phase 1c: partition pairs into buckets ----------------
__global__ __launch_bounds__(256) void bin_scatter_kernel(
    const int* __restrict__ src, const int* __restrict__ dst,
    const int* __restrict__ wbase, int2* __restrict__ pairs) {
  __shared__ int cur[NBUCK];
  for (int i = threadIdx.x; i < NBUCK; i += 256)
    cur[i] = wbase[i * BIN_NBLK + blockIdx.x];
  __syncthreads();
  int beg = blockIdx.x * BIN_CHUNK;
  int end = min(beg + BIN_CHUNK, N_EDGES);
  for (int e = beg + threadIdx.x; e < end; e += 256) {
    int d = dst[e];
    int pos = atomicAdd(&cur[d >> 8], 1);
    pairs[pos] = make_int2(src[e], d);
  }
}

// ---------------- Phase 2: exact sort within each bucket ----------------
// One WG per bucket: 256-node window, sorted_src region ~16 KB stays in one
// XCD's L2, lines fully written before eviction. Also emits CSR offsets.
__global__ __launch_bounds__(256) void bucket_sort_kernel(
    const int2* __restrict__ pairs, const int* __restrict__ wbase,
    int* __restrict__ offsets, int* __restrict__ sorted_src) {
  __shared__ int hist[256];
  __shared__ int excl[256];
  int b = blockIdx.x;
  int t = threadIdx.x;
  int pbeg = wbase[b * BIN_NBLK];
  int pend = wbase[(b + 1) * BIN_NBLK];  // b==NBUCK-1 hits the sentinel
  hist[t] = 0;
  __syncthreads();
  for (int i = pbeg + t; i < pend; i += 256)
    atomicAdd(&hist[pairs[i].y & 255], 1);
  __syncthreads();
  int v = hist[t];
  excl[t] = v;
  __syncthreads();
  for (int off = 1; off < 256; off <<= 1) {
    int u = (t >= off) ? excl[t - off] : 0;
    __syncthreads();
    excl[t] += u;
    __syncthreads();
  }
  int my_excl = excl[t] - v;
  int node = (b << 8) + t;
  if (node < N_NODES) offsets[node] = pbeg + my_excl;
  if (b == NBUCK - 1 && t == 0) offsets[N_NODES] = N_EDGES;
  __syncthreads();
  hist[t] = my_excl;  // reuse as per-node cursor (within-bucket position)
  __syncthreads();
  for (int i = pbeg + t; i < pend; i += 256) {
    int2 p = pairs[i];
    int pos = atomicAdd(&hist[p.y & 255], 1);
    sorted_src[pbeg + pos] = p.x;
  }
}

// ---------------- Gather + softmax + epilogue (one wave per node) ----------
__global__ __launch_bounds__(256) void gather_kernel(
    const float* __restrict__ h, const float* __restrict__ a,
    const int* __restrict__ offsets, const int* __restrict__ sorted_src,
    float* __restrict__ out) {
  int wave = (blockIdx.x * 256 + threadIdx.x) >> 6;
  int lane = threadIdx.x & 63;
  if (wave >= N_NODES) return;
  int n = wave;
  int beg = offsets[n];
  int end = offsets[n + 1];
  int g = lane >> 4;
  int l16 = lane & 15;

  const float4* h4 = (const float4*)h;
  float4 hd = h4[(size_t)n * (OUT_DIM / 4) + l16];
  float4 av = ((const float4*)a)[l16];

  float4 acc = make_float4(0.f, 0.f, 0.f, 0.f);
  float den = 0.f;

  for (int i = beg + g; i < end; i += 4) {
    int s = sorted_src[i];
    float4 hs = h4[(size_t)s * (OUT_DIM / 4) + l16];
    float4 df;
    df.x = hd.x - hs.x;
    df.y = hd.y - hs.y;
    df.z = hd.z - hs.z;
    df.w = hd.w - hs.w;
    float p = df.x * av.x + df.y * av.y + df.z * av.z + df.w * av.w;
    p += __shfl_xor(p, 1);
    p += __shfl_xor(p, 2);
    p += __shfl_xor(p, 4);
    p += __shfl_xor(p, 8);
    float ex = expf(tanhf(p));
    den += ex;
    acc.x += ex * df.x;
    acc.y += ex * df.y;
    acc.z += ex * df.z;
    acc.w += ex * df.w;
  }

  acc.x += __shfl_xor(acc.x, 16);
  acc.x += __shfl_xor(acc.x, 32);
  acc.y += __shfl_xor(acc.y, 16);
  acc.y += __shfl_xor(acc.y, 32);
  acc.z += __shfl_xor(acc.z, 16);
  acc.z += __shfl_xor(acc.z, 32);
  acc.w += __shfl_xor(acc.w, 16);
  acc.w += __shfl_xor(acc.w, 32);
  den += __shfl_xor(den, 16);
  den += __shfl_xor(den, 32);

  if (g == 0) {
    float inv = den > 0.f ? 1.f / den : 0.f;
    float4 r;
    r.x = fmaxf(hd.x + acc.x * inv, 0.f);
    r.y = fmaxf(hd.y + acc.y * inv, 0.f);
    r.z = fmaxf(hd.z + acc.z * inv, 0.f);
    r.w = fmaxf(hd.w + acc.w * inv, 0.f);
    ((float4*)out)[(size_t)n * (OUT_DIM / 4) + l16] = r;
  }
}

extern "C" void kernel_launch(void* const* d_in, const int* in_sizes, int n_in,
                              void* d_out, int out_size, void* d_ws,
                              size_t ws_size, hipStream_t stream) {
  const float* h_init = (const float*)d_in[0];
  const float* W1 = (const float*)d_in[1];
  const float* a = (const float*)d_in[2];
  const int* src = (const int*)d_in[3];
  const int* dst = (const int*)d_in[4];
  float* out = (float*)d_out;

  // workspace layout (~45.5 MB)
  float* h = (float*)d_ws;                          // 6.4M floats
  int2* pairs = (int2*)(h + (size_t)N_NODES * OUT_DIM);  // 1.6M int2
  int* wbase = (int*)(pairs + N_EDGES);             // 39101
  int* offsets = wbase + CNT_TOTAL + 1;             // 100001
  int* sorted_src = offsets + (N_NODES + 1);        // 1.6M
  int* blk_cnt = sorted_src + N_EDGES;              // 39100

  proj_kernel<<<(N_NODES + 255) / 256, 256, 0, stream>>>(h_init, W1, h);
  bin_count_kernel<<<BIN_NBLK, 256, 0, stream>>>(dst, blk_cnt);
  scan_cnt_kernel<<<1, 1024, 0, stream>>>(blk_cnt, wbase);
  bin_scatter_kernel<<<BIN_NBLK, 256, 0, stream>>>(src, dst, wbase, pairs);
  bucket_sort_kernel<<<NBUCK, 256, 0, stream>>>(pairs, wbase, offsets,
                                                sorted_src);
  gather_kernel<<<(N_NODES * 64 + 255) / 256, 256, 0, stream>>>(
      h, a, offsets, sorted_src, out);
}